// Round 9
// baseline (383.235 us; speedup 1.0000x reference)
//
#include <hip/hip_runtime.h>
#include <hip/hip_bf16.h>

// GPT2 block fwd: B=2,S=2048,D=1024,H=16,DH=64,F=4096. fp32 in/out, bf16 MFMA.
// ws layout (bytes):
//   [0,24M)   qkv bf16 [4096][3072]  (V cols unused; slot reused by ffn 32MB)
//   [24M,32M) vt bf16 [32 bh][64 d][2048 s]  (written by QKV GEMM epilogue)
//   [32M,40M) hbuf bf16: h (LN1 out), later attention output o
//   [40M,56M) add1 fp32 [4096][1024]
//   [56M,64M) h2 bf16
//   [64M,70M) qkvT bf16 | [70M,72M) woT | [72M,80M) w1T | [80M,88M) w2T
//   [88M,..)  bias_qkv fp32 [3072]
// total ~88MB.

#define BDIM 1024
#define SEQ 2048
#define NH 16
#define DHEAD 64
#define FDIM 4096
#define QKVD 3072

typedef __attribute__((ext_vector_type(8))) short short8v;
typedef __attribute__((ext_vector_type(4))) float floatx4;

__device__ __forceinline__ unsigned short f2bf(float f) {
    unsigned int u = __float_as_uint(f);
    unsigned int r = u + 0x7FFFu + ((u >> 16) & 1u);
    return (unsigned short)(r >> 16);
}
__device__ __forceinline__ unsigned int pack2bf(float a, float b) {
    return (unsigned int)f2bf(a) | ((unsigned int)f2bf(b) << 16);
}

__device__ __forceinline__ void load16_lds(const unsigned short* g, short* l) {
    __builtin_amdgcn_global_load_lds((const __attribute__((address_space(1))) void*)g,
                                     (__attribute__((address_space(3))) void*)l, 16, 0, 0);
}

// ---------------- batched weight fp32 [K,N] -> bf16 [N,K] transpose ----------
__global__ __launch_bounds__(256) void transpose_all(const float* __restrict__ wq,
                                                     const float* __restrict__ wk,
                                                     const float* __restrict__ wv,
                                                     const float* __restrict__ wo,
                                                     const float* __restrict__ w1,
                                                     const float* __restrict__ w2,
                                                     unsigned short* __restrict__ qkvT,
                                                     unsigned short* __restrict__ woT,
                                                     unsigned short* __restrict__ w1T,
                                                     unsigned short* __restrict__ w2T) {
    const int g = blockIdx.x;
    const float* W;
    unsigned short* Wt;
    int K, N, tx, ty;
    if (g < 4096) {
        const int w = g >> 10, tile = g & 1023;
        tx = tile & 31; ty = tile >> 5; K = 1024; N = 1024;
        W = (w == 0) ? wq : (w == 1) ? wk : (w == 2) ? wv : wo;
        Wt = (w == 3) ? woT : qkvT + (size_t)w * 1024 * 1024;
    } else if (g < 8192) {
        const int tile = g - 4096;
        tx = tile & 127; ty = tile >> 7; K = 1024; N = 4096;
        W = w1; Wt = w1T;
    } else {
        const int tile = g - 8192;
        tx = tile & 31; ty = tile >> 5; K = 4096; N = 1024;
        W = w2; Wt = w2T;
    }
    __shared__ float tile[32][33];
    const int t = threadIdx.x;
    const int r = t >> 3, c4 = (t & 7) * 4;
    const int n0 = tx * 32, k0 = ty * 32;
    float4 p = *(const float4*)(W + (size_t)(k0 + r) * N + n0 + c4);
    tile[r][c4 + 0] = p.x;
    tile[r][c4 + 1] = p.y;
    tile[r][c4 + 2] = p.z;
    tile[r][c4 + 3] = p.w;
    __syncthreads();
    ushort4 ou;
    ou.x = f2bf(tile[c4 + 0][r]);
    ou.y = f2bf(tile[c4 + 1][r]);
    ou.z = f2bf(tile[c4 + 2][r]);
    ou.w = f2bf(tile[c4 + 3][r]);
    *(ushort4*)(Wt + (size_t)(n0 + r) * K + k0 + c4) = ou;
}

__global__ void concat_bias(const float* __restrict__ a, const float* __restrict__ b,
                            const float* __restrict__ c, float* __restrict__ out) {
    int i = blockIdx.x * 256 + threadIdx.x;
    out[i] = (i < 1024) ? a[i] : (i < 2048 ? b[i - 1024] : c[i - 2048]);
}

// ---------------- LayerNorm: fp32 in -> bf16 out ----------------
__global__ __launch_bounds__(256) void ln_kernel(const float* __restrict__ x,
                                                 const float* __restrict__ g,
                                                 const float* __restrict__ bb,
                                                 unsigned short* __restrict__ out) {
    const int row = blockIdx.x;
    const int t = threadIdx.x;
    const int c = t * 4;
    float4 p = *(const float4*)(x + (size_t)row * BDIM + c);
    float s = p.x + p.y + p.z + p.w;
    float sq = p.x * p.x + p.y * p.y + p.z * p.z + p.w * p.w;
    for (int off = 1; off < 64; off <<= 1) {
        s += __shfl_xor(s, off);
        sq += __shfl_xor(sq, off);
    }
    __shared__ float ssum[4], ssq[4];
    const int wave = t >> 6, lane = t & 63;
    if (lane == 0) { ssum[wave] = s; ssq[wave] = sq; }
    __syncthreads();
    s = ssum[0] + ssum[1] + ssum[2] + ssum[3];
    sq = ssq[0] + ssq[1] + ssq[2] + ssq[3];
    const float mean = s * (1.0f / BDIM);
    const float var = sq * (1.0f / BDIM) - mean * mean;
    const float rstd = rsqrtf(var + 1e-5f);
    float4 gg = *(const float4*)(g + c);
    float4 bv = *(const float4*)(bb + c);
    ushort4 o;
    o.x = f2bf((p.x - mean) * rstd * gg.x + bv.x);
    o.y = f2bf((p.y - mean) * rstd * gg.y + bv.y);
    o.z = f2bf((p.z - mean) * rstd * gg.z + bv.z);
    o.w = f2bf((p.w - mean) * rstd * gg.w + bv.w);
    *(ushort4*)(out + (size_t)row * BDIM + c) = o;
}

// ---------------- MFMA GEMM, BK=64 (two BK=32 sub-tiles per barrier) ----------
// QSCALE: output cols < 1024 scaled by 0.125 (pre-scales Q for attention).
// VOUT: output cols >= 2048 (V block of QKV) written transposed to vtout.
template <int BN, int RES, int GELU, int OBF16, int QSCALE = 0, int VOUT = 0>
__global__ __launch_bounds__(256, 3) void mfma_gemm(const unsigned short* __restrict__ A,
                                                    const unsigned short* __restrict__ Bt,
                                                    const float* __restrict__ bias,
                                                    const float* __restrict__ res,
                                                    void* __restrict__ Cv,
                                                    unsigned short* __restrict__ vtout,
                                                    int M, int N, int K) {
    constexpr int MI = (BN == 128) ? 4 : 2;
    constexpr int CHB = BN * 4;  // 16B-chunks per B k-half
    __shared__ short As[2][128 * 32];
    __shared__ short Bs[2][BN * 32];
    const int t = threadIdx.x;
    const int wave = t >> 6, lane = t & 63;
    const int m0 = blockIdx.y * 128, n0 = blockIdx.x * BN;
    const int wmrow = (BN == 128) ? (wave & 1) * 64 : wave * 32;
    const int wnrow = (BN == 128) ? (wave >> 1) * 64 : 0;
    const int mlane = lane & 15, quad = lane >> 4;

    floatx4 acc[MI][4];
#pragma unroll
    for (int mi = 0; mi < MI; ++mi)
#pragma unroll
        for (int ni = 0; ni < 4; ++ni) {
            floatx4 z = {0.0f, 0.0f, 0.0f, 0.0f};
            acc[mi][ni] = z;
        }

    for (int k0 = 0; k0 < K; k0 += 64) {
        __syncthreads();
#pragma unroll
        for (int j = 0; j < 4; ++j) {
            const int c = j * 256 + t;
            const int hh = c >> 9, cc = c & 511;
            load16_lds(A + (size_t)(m0 + (cc >> 2)) * K + k0 + hh * 32 + (cc & 3) * 8,
                       &As[hh][cc * 8]);
        }
#pragma unroll
        for (int j = 0; j < CHB / 128; ++j) {
            const int c = j * 256 + t;
            const int hh = c / CHB, cc = c % CHB;
            load16_lds(Bt + (size_t)(n0 + (cc >> 2)) * K + k0 + hh * 32 + (cc & 3) * 8,
                       &Bs[hh][cc * 8]);
        }
        __syncthreads();
#pragma unroll
        for (int hh = 0; hh < 2; ++hh) {
            short8v a[MI], b[4];
#pragma unroll
            for (int mi = 0; mi < MI; ++mi)
                a[mi] = *(const short8v*)&As[hh][(wmrow + mi * 16 + mlane) * 32 + quad * 8];
#pragma unroll
            for (int ni = 0; ni < 4; ++ni)
                b[ni] = *(const short8v*)&Bs[hh][(wnrow + ni * 16 + mlane) * 32 + quad * 8];
#pragma unroll
            for (int mi = 0; mi < MI; ++mi)
#pragma unroll
                for (int ni = 0; ni < 4; ++ni)
                    acc[mi][ni] = __builtin_amdgcn_mfma_f32_16x16x32_bf16(a[mi], b[ni], acc[mi][ni], 0, 0, 0);
        }
    }
#pragma unroll
    for (int mi = 0; mi < MI; ++mi) {
#pragma unroll
        for (int ni = 0; ni < 4; ++ni) {
            const int col = n0 + wnrow + ni * 16 + mlane;
            const float bv = bias[col];
            const int row0 = m0 + wmrow + mi * 16 + quad * 4;
            if (VOUT && col >= 2048) {
                const int vd = col - 2048;
                const int bb = row0 >> 11, ss = row0 & 2047;
                uint2 pk;
                pk.x = pack2bf(acc[mi][ni][0] + bv, acc[mi][ni][1] + bv);
                pk.y = pack2bf(acc[mi][ni][2] + bv, acc[mi][ni][3] + bv);
                *(uint2*)(vtout + ((size_t)(bb * NH + (vd >> 6)) * DHEAD + (vd & 63)) * SEQ + ss) = pk;
            } else {
#pragma unroll
                for (int rg = 0; rg < 4; ++rg) {
                    const int row = row0 + rg;
                    float v = acc[mi][ni][rg] + bv;
                    if (RES) v += res[(size_t)row * N + col];
                    if (GELU) v = 0.5f * v * (1.0f + erff(v * 0.70710678118654752f));
                    if (QSCALE && col < 1024) v *= 0.125f;
                    if (OBF16)
                        ((unsigned short*)Cv)[(size_t)row * N + col] = f2bf(v);
                    else
                        ((float*)Cv)[(size_t)row * N + col] = v;
                }
            }
        }
    }
}

// ---------------- MFMA flash attention (causal), uniform-work blocks ----------
// 256 blocks x 512 threads (8 waves). Block g: bh = g&31, j = g>>5. Wave w owns
// query rows qi = j + 8w (32 queries, 2 ng of 16). All 8 waves share one K/V^T
// LDS staging; block loops key-windows of 64 to kmax = ceil((j+57)*32/64)*64 —
// constant work per block BY CONSTRUCTION (immune to workgroup->CU mapping).
// Waves past their causal kend idle through barriers. Q pre-scaled by 0.125.
__global__ __launch_bounds__(512, 4) void attn_kernel(const unsigned short* __restrict__ qkv,
                                                      const unsigned short* __restrict__ vt,
                                                      unsigned short* __restrict__ o) {
    const int g = blockIdx.x;
    const int bh = g & 31;
    const int j = g >> 5;                 // 0..7
    const int h = bh & 15, b = bh >> 4;
    const int t = threadIdx.x;
    const int wave = t >> 6, lane = t & 63;
    const int mlane = lane & 15, quad = lane >> 4;
    const int qi = j + 8 * wave;          // query-wave index 0..63
    const int wq0 = qi * 32;
    const size_t bS = (size_t)b * SEQ;

    __shared__ unsigned short Ks[64][72];                       // [key][dim]
    __shared__ unsigned short Vs[64][72];                       // [dim][key]
    __shared__ __align__(16) unsigned short plds[8][2][16][72]; // [wave][ng][q][key]

    short8v qf[2][2];
#pragma unroll
    for (int ng = 0; ng < 2; ++ng) {
        const unsigned short* qrow = qkv + (bS + wq0 + ng * 16 + mlane) * QKVD + h * DHEAD;
        qf[ng][0] = *(const short8v*)(qrow + quad * 8);
        qf[ng][1] = *(const short8v*)(qrow + 32 + quad * 8);
    }

    const unsigned short* kbase = qkv + bS * QKVD + 1024 + h * DHEAD;
    const unsigned short* vbase = vt + ((size_t)bh) * DHEAD * SEQ;

    // staging: 1024 chunks per 64-key window (K 512 + V 512), 2 per thread
    const int sr = t >> 3, so = (t & 7) * 8;  // row 0..63, 16B offset
    const unsigned short* kg = kbase + (size_t)sr * QKVD + so;
    const unsigned short* vg = vbase + (size_t)sr * SEQ + so;

    floatx4 ot[2][4];
#pragma unroll
    for (int ng = 0; ng < 2; ++ng)
#pragma unroll
        for (int mt = 0; mt < 4; ++mt) { floatx4 z = {0, 0, 0, 0}; ot[ng][mt] = z; }
    float m_r[2] = {-INFINITY, -INFINITY}, l_r[2] = {0.0f, 0.0f};

    const int kend = wq0 + 32;                      // this wave's causal limit
    const int kmax = (((j + 57) * 32) + 63) & ~63;  // block loop limit (uniform in j)

    uint4 kr = *(const uint4*)kg;
    uint4 vr = *(const uint4*)vg;

    for (int k0 = 0; k0 < kmax; k0 += 64) {
        *(uint4*)&Ks[sr][so] = kr;
        *(uint4*)&Vs[sr][so] = vr;
        __syncthreads();
        if (k0 + 64 < kmax) {
            kr = *(const uint4*)(kg + (size_t)(k0 + 64) * QKVD);
            vr = *(const uint4*)(vg + (k0 + 64));
        }
        if (k0 < kend) {
            // ---- S^T = K·Q^T over active 16-key tiles ----
            floatx4 st[2][4];
#pragma unroll
            for (int ng = 0; ng < 2; ++ng)
#pragma unroll
                for (int kt = 0; kt < 4; ++kt) {
                    floatx4 mz = {-1e30f, -1e30f, -1e30f, -1e30f};
                    st[ng][kt] = mz;
                }
#pragma unroll
            for (int kt = 0; kt < 4; ++kt) {
                if (k0 + kt * 16 < kend) {
                    short8v kfa = *(const short8v*)&Ks[kt * 16 + mlane][quad * 8];
                    short8v kfb = *(const short8v*)&Ks[kt * 16 + mlane][32 + quad * 8];
#pragma unroll
                    for (int ng = 0; ng < 2; ++ng) {
                        floatx4 z = {0, 0, 0, 0};
                        st[ng][kt] = __builtin_amdgcn_mfma_f32_16x16x32_bf16(kfa, qf[ng][0], z, 0, 0, 0);
                        st[ng][kt] = __builtin_amdgcn_mfma_f32_16x16x32_bf16(kfb, qf[ng][1], st[ng][kt], 0, 0, 0);
                    }
                }
            }
            // ---- causal mask (only the window straddling the diagonal) ----
            if (k0 + 64 >= kend) {
#pragma unroll
                for (int ng = 0; ng < 2; ++ng)
#pragma unroll
                    for (int kt = 0; kt < 4; ++kt)
#pragma unroll
                        for (int rg = 0; rg < 4; ++rg)
                            if (k0 + kt * 16 + quad * 4 + rg > wq0 + ng * 16 + mlane)
                                st[ng][kt][rg] = -1e30f;
            }
            // ---- online softmax + P^T to LDS ----
#pragma unroll
            for (int ng = 0; ng < 2; ++ng) {
                float tm = st[ng][0][0];
#pragma unroll
                for (int kt = 0; kt < 4; ++kt)
#pragma unroll
                    for (int rg = 0; rg < 4; ++rg) tm = fmaxf(tm, st[ng][kt][rg]);
                tm = fmaxf(tm, __shfl_xor(tm, 16));
                tm = fmaxf(tm, __shfl_xor(tm, 32));
                const float newm = fmaxf(m_r[ng], tm);
                const float alpha = __expf(m_r[ng] - newm);
                m_r[ng] = newm;
                float p[4][4], psum = 0.0f;
#pragma unroll
                for (int kt = 0; kt < 4; ++kt)
#pragma unroll
                    for (int rg = 0; rg < 4; ++rg) {
                        p[kt][rg] = __expf(st[ng][kt][rg] - newm);
                        psum += p[kt][rg];
                    }
                psum += __shfl_xor(psum, 16);
                psum += __shfl_xor(psum, 32);
                l_r[ng] = l_r[ng] * alpha + psum;
#pragma unroll
                for (int mt = 0; mt < 4; ++mt)
#pragma unroll
                    for (int rg = 0; rg < 4; ++rg) ot[ng][mt][rg] *= alpha;
#pragma unroll
                for (int kt = 0; kt < 4; ++kt) {
                    uint2 pk;
                    pk.x = pack2bf(p[kt][0], p[kt][1]);
                    pk.y = pack2bf(p[kt][2], p[kt][3]);
                    *(uint2*)&plds[wave][ng][mlane][kt * 16 + quad * 4] = pk;
                }
            }
            // ---- O^T += V^T · P^T over active 32-key halves ----
#pragma unroll
            for (int kh = 0; kh < 2; ++kh) {
                if (k0 + kh * 32 < kend) {
                    short8v vf[4];
#pragma unroll
                    for (int mt = 0; mt < 4; ++mt)
                        vf[mt] = *(const short8v*)&Vs[mt * 16 + mlane][kh * 32 + quad * 8];
#pragma unroll
                    for (int ng = 0; ng < 2; ++ng) {
                        short8v pf = *(const short8v*)&plds[wave][ng][mlane][kh * 32 + quad * 8];
#pragma unroll
                        for (int mt = 0; mt < 4; ++mt)
                            ot[ng][mt] = __builtin_amdgcn_mfma_f32_16x16x32_bf16(vf[mt], pf, ot[ng][mt], 0, 0, 0);
                    }
                }
            }
        }
        __syncthreads();
    }

    // epilogue
#pragma unroll
    for (int ng = 0; ng < 2; ++ng) {
        const float inv = 1.0f / l_r[ng];
        unsigned short* orow = o + (bS + wq0 + ng * 16 + mlane) * BDIM + h * DHEAD;
#pragma unroll
        for (int mt = 0; mt < 4; ++mt) {
            uint2 pk;
            pk.x = pack2bf(ot[ng][mt][0] * inv, ot[ng][mt][1] * inv);
            pk.y = pack2bf(ot[ng][mt][2] * inv, ot[ng][mt][3] * inv);
            *(uint2*)(orow + mt * 16 + quad * 4) = pk;
        }
    }
}

extern "C" void kernel_launch(void* const* d_in, const int* in_sizes, int n_in,
                              void* d_out, int out_size, void* d_ws, size_t ws_size,
                              hipStream_t stream) {
    const int M = 2 * SEQ;  // 4096

    const float* x = (const float*)d_in[0];
    const float* ln1_g = (const float*)d_in[1];
    const float* ln1_b = (const float*)d_in[2];
    const float* wq = (const float*)d_in[3];
    const float* bq = (const float*)d_in[4];
    const float* wk = (const float*)d_in[5];
    const float* bk = (const float*)d_in[6];
    const float* wv = (const float*)d_in[7];
    const float* bv = (const float*)d_in[8];
    const float* wo = (const float*)d_in[9];
    const float* bo = (const float*)d_in[10];
    const float* ln2_g = (const float*)d_in[11];
    const float* ln2_b = (const float*)d_in[12];
    const float* w1 = (const float*)d_in[13];
    const float* b1 = (const float*)d_in[14];
    const float* w2 = (const float*)d_in[15];
    const float* b2 = (const float*)d_in[16];

    char* wsb = (char*)d_ws;
    unsigned short* qkv = (unsigned short*)wsb;                    // [M][3072]
    unsigned short* ffn = (unsigned short*)wsb;                    // [M][4096] (later)
    unsigned short* vt = (unsigned short*)(wsb + (24u << 20));     // [32][64][2048]
    unsigned short* hbuf = (unsigned short*)(wsb + (32u << 20));   // h then o
    float* add1 = (float*)(wsb + (40u << 20));
    unsigned short* h2 = (unsigned short*)(wsb + (56u << 20));
    unsigned short* qkvT = (unsigned short*)(wsb + (64u << 20));
    unsigned short* woT = (unsigned short*)(wsb + (70u << 20));
    unsigned short* w1T = (unsigned short*)(wsb + (72u << 20));
    unsigned short* w2T = (unsigned short*)(wsb + (80u << 20));
    float* bqkv = (float*)(wsb + (88u << 20));

    // 0. weight convert+transpose (one launch), bias concat
    transpose_all<<<12288, 256, 0, stream>>>(wq, wk, wv, wo, w1, w2, qkvT, woT, w1T, w2T);
    concat_bias<<<12, 256, 0, stream>>>(bq, bk, bv, bqkv);

    // 1. h = LN1(x) -> bf16
    ln_kernel<<<M, 256, 0, stream>>>(x, ln1_g, ln1_b, hbuf);

    // 2. qkv = h @ [wq|wk|wv] + bias; Q pre-scaled 0.125; V written transposed to vt
    mfma_gemm<128, 0, 0, 1, 1, 1><<<dim3(QKVD / 128, M / 128), 256, 0, stream>>>(
        hbuf, qkvT, bqkv, nullptr, qkv, vt, M, QKVD, 1024);

    // 3. o = causal_attention(qkv, vt) -> hbuf
    attn_kernel<<<256, 512, 0, stream>>>(qkv, vt, hbuf);

    // 4. add1 = o @ wo + bo + x (fp32)
    mfma_gemm<64, 1, 0, 0><<<dim3(1024 / 64, M / 128), 256, 0, stream>>>(
        hbuf, woT, bo, x, add1, nullptr, M, 1024, 1024);

    // 5. h2 = LN2(add1) -> bf16
    ln_kernel<<<M, 256, 0, stream>>>(add1, ln2_g, ln2_b, h2);

    // 6. ffn = gelu(h2 @ w1 + b1) -> bf16 (overwrites qkv+vt region; both dead)
    mfma_gemm<128, 0, 1, 1><<<dim3(FDIM / 128, M / 128), 256, 0, stream>>>(
        h2, w1T, b1, nullptr, ffn, nullptr, M, FDIM, 1024);

    // 7. out = ffn @ w2 + b2 + add1 -> fp32 d_out
    mfma_gemm<64, 1, 0, 0><<<dim3(1024 / 64, M / 128), 256, 0, stream>>>(
        ffn, w2T, b2, add1, (float*)d_out, nullptr, M, 1024, FDIM);
}